// Round 9
// baseline (671.325 us; speedup 1.0000x reference)
//
#include <hip/hip_runtime.h>
#include <hip/hip_bf16.h>
#include <cmath>

// Problem dims (fixed): B=16, T=1024, IN=1024, H=1024
// M = B*T = 16384, K1 = 1024, N1 = 1024, K2 = 2048, N2 = 1024
//
// Numerics contract (validated round 5): GEMM1 must be a sequential
// ascending-k f32 FMA chain per output element + separate f32 bias add
// (mirrors the np golden's BLAS sgemm). Scan mirrors numpy f32 op-for-op.
// GEMM2 (smooth tanh) is bf16 MFMA.
//
// Round 9:
//  - gemm1: r6 structure (padded LDF=36, conflict-free; NO register-carried
//    prefetch -- proven bad in r7/r8) + ping-pong LDS double-buffer with a
//    SINGLE barrier per K-step (stage buf[t&1]; barrier; compute; next iter
//    writes the other buffer so no trailing barrier is needed).
//  - scan: 16-deep static prefetch ring (loads are independent of the
//    recurrence; hoist a full batch ahead), 256 blocks x 64 threads.

typedef __attribute__((ext_vector_type(8))) __bf16 bf16x8;
typedef __attribute__((ext_vector_type(4))) __bf16 bf16x4;
typedef __attribute__((ext_vector_type(4))) float  f32x4;

#define LDT 40  // bf16 LDS pad (GEMM2): 80B rows
#define LDF 36  // f32 LDS pad (GEMM1): 144B rows — measured 0 bank conflicts

// ---------------------------------------------------------------------------
// GEMM1 (f32 FMA-chain): I[m,h] = fadd( fmaf-chain_{k=0..1023}, b_in[h] )
// ping-pong LDS dbuf, one barrier per K-step.
// ---------------------------------------------------------------------------
__global__ __launch_bounds__(256)
void gemm1_f32chain_kernel(const float* __restrict__ X,
                           const float* __restrict__ W,
                           const float* __restrict__ bias,
                           float* __restrict__ I)
{
    __shared__ __align__(16) float sA[2][128][LDF];
    __shared__ __align__(16) float sB[2][128][LDF];

    const int tid  = threadIdx.x;
    const int bn   = blockIdx.x;      // 0..7
    const int bm   = blockIdx.y;      // 0..127
    const int row0 = bm * 128;
    const int col0 = bn * 128;
    const int tx   = tid & 15;
    const int ty   = tid >> 4;

    // staging geometry (4 float4 chunks per matrix per thread)
    int rr[4], cc[4];
    #pragma unroll
    for (int i = 0; i < 4; ++i) {
        int q = tid + i * 256;        // 0..1023
        rr[i] = q >> 3;               // row 0..127
        cc[i] = (q & 7) * 4;          // col 0..28
    }

    float acc[8][8];
    #pragma unroll
    for (int i = 0; i < 8; ++i)
        #pragma unroll
        for (int j = 0; j < 8; ++j)
            acc[i][j] = 0.0f;

    for (int t = 0; t < 32; ++t) {
        const int p  = t & 1;
        const int k0 = t * 32;

        // stage tile t into buf p (global -> reg -> LDS, immediate store;
        // no registers live across the compute phase)
        #pragma unroll
        for (int i = 0; i < 4; ++i) {
            f32x4 va = *(const f32x4*)&X[(size_t)(row0 + rr[i]) * 1024 + k0 + cc[i]];
            f32x4 vb = *(const f32x4*)&W[(size_t)(col0 + rr[i]) * 1024 + k0 + cc[i]];
            *(f32x4*)&sA[p][rr[i]][cc[i]] = va;
            *(f32x4*)&sB[p][rr[i]][cc[i]] = vb;
        }
        __syncthreads();   // buf p ready; also fences: everyone done reading
                           // buf p from iteration t-2 (program order: compute
                           // t-2 precedes stage t-1 precedes this barrier... )

        // compute: FMA order strictly ascending k (kk group asc, q asc)
        #pragma unroll
        for (int kk = 0; kk < 32; kk += 4) {
            f32x4 a4[8], b4[8];
            #pragma unroll
            for (int i = 0; i < 8; ++i) a4[i] = *(const f32x4*)&sA[p][ty + 16 * i][kk];
            #pragma unroll
            for (int j = 0; j < 8; ++j) b4[j] = *(const f32x4*)&sB[p][tx + 16 * j][kk];
            #pragma unroll
            for (int q = 0; q < 4; ++q)
                #pragma unroll
                for (int i = 0; i < 8; ++i)
                    #pragma unroll
                    for (int j = 0; j < 8; ++j)
                        acc[i][j] = fmaf(a4[i][q], b4[j][q], acc[i][j]);
        }
        // no trailing barrier: next iteration stages the OTHER buffer
    }

    #pragma unroll
    for (int i = 0; i < 8; ++i)
        #pragma unroll
        for (int j = 0; j < 8; ++j) {
            int rg = row0 + ty + 16 * i;
            int cg = col0 + tx + 16 * j;
            I[(size_t)rg * 1024 + cg] = __fadd_rn(acc[i][j], bias[cg]);
        }
}

// ---------------------------------------------------------------------------
// Scan, numpy-f32 mirror (validated):
//   alpha = expf(-logaddexpf(lt,0)) via round-to-f32 of f64 libm
//   v = fadd(fmul(alpha, v), I); spike = v > thr; v = fmul(v, 1-spike)
// 16-deep static prefetch ring; 1 wave per block, 256 blocks (all CUs busy).
// ---------------------------------------------------------------------------
__global__ __launch_bounds__(64)
void hsru_scan_f32_kernel(const float* __restrict__ I,
                          const float* __restrict__ leak,
                          const float* __restrict__ thr,
                          __bf16* __restrict__ comb)
{
    int g = blockIdx.x * 64 + threadIdx.x;  // 0..16383
    int b = g >> 10;
    int h = g & 1023;

    float lt = leak[h];
    float e     = (float)exp(-(double)fabsf(lt));
    float l1    = (float)log1p((double)e);
    float sp    = __fadd_rn(fmaxf(lt, 0.0f), l1);
    float alpha = (float)exp(-(double)sp);
    float th    = thr[h];

    const float* Ip = I    + (size_t)b * (1024 * 1024) + h;
    __bf16*      cp = comb + (size_t)b * (1024 * 2048) + h;

    float buf[16], nxt[16];
    #pragma unroll
    for (int j = 0; j < 16; ++j) buf[j] = Ip[(size_t)j * 1024];

    float v = 0.0f;
    for (int t0 = 0; t0 < 1024; t0 += 16) {
        if (t0 + 16 < 1024) {
            #pragma unroll
            for (int j = 0; j < 16; ++j)
                nxt[j] = Ip[(size_t)(t0 + 16 + j) * 1024];
        }
        #pragma unroll
        for (int j = 0; j < 16; ++j) {
            float cur = buf[j];
            v = __fadd_rn(__fmul_rn(alpha, v), cur);
            float spike = (v > th) ? 1.0f : 0.0f;
            v = __fmul_rn(v, __fsub_rn(1.0f, spike));
            cp[(size_t)(t0 + j) * 2048]        = (__bf16)v;
            cp[(size_t)(t0 + j) * 2048 + 1024] = (__bf16)spike;
        }
        if (t0 + 16 < 1024) {
            #pragma unroll
            for (int j = 0; j < 16; ++j) buf[j] = nxt[j];
        }
    }
}

// ---------------------------------------------------------------------------
// W_out f32 -> bf16 pre-convert (once per launch; 2M elements)
// ---------------------------------------------------------------------------
__global__ __launch_bounds__(256)
void wcvt_kernel(const float* __restrict__ W, __bf16* __restrict__ Wb)
{
    int idx = (blockIdx.x * 256 + threadIdx.x) * 8;   // 8 elements/thread
    f32x4 v0 = *(const f32x4*)&W[idx];
    f32x4 v1 = *(const f32x4*)&W[idx + 4];
    bf16x8 o;
    #pragma unroll
    for (int j = 0; j < 4; ++j) { o[j] = (__bf16)v0[j]; o[4 + j] = (__bf16)v1[j]; }
    *(bf16x8*)&Wb[idx] = o;
}

// ---------------------------------------------------------------------------
// GEMM2: out = tanh(combined @ Wb^T + b_out), bf16 MFMA (smooth path).
// A = comb [M,2048] bf16, B = Wb [1024,2048] bf16 (pre-converted)
// ---------------------------------------------------------------------------
__global__ __launch_bounds__(256)
void gemm2_kernel(const __bf16* __restrict__ A,
                  const __bf16* __restrict__ Wb,
                  const float* __restrict__ bias,
                  float* __restrict__ O)
{
    __shared__ __align__(16) __bf16 sA[128][LDT];
    __shared__ __align__(16) __bf16 sB[128][LDT];

    const int tid  = threadIdx.x;
    const int bn   = blockIdx.x;
    const int bm   = blockIdx.y;
    const int row0 = bm * 128;
    const int col0 = bn * 128;

    const int lane = tid & 63;
    const int wid  = tid >> 6;
    const int wm   = (wid >> 1) * 64;
    const int wn   = (wid & 1) * 64;

    f32x4 acc[4][4];
    #pragma unroll
    for (int i = 0; i < 4; ++i)
        #pragma unroll
        for (int j = 0; j < 4; ++j)
            acc[i][j] = f32x4{0.f, 0.f, 0.f, 0.f};

    const int frow  = lane & 15;
    const int fkoff = (lane >> 4) * 8;

    for (int k0 = 0; k0 < 2048; k0 += 32) {
        #pragma unroll
        for (int i = 0; i < 2; ++i) {
            int q  = tid + i * 256;   // 0..511
            int r  = q >> 2;          // 0..127
            int c8 = (q & 3) * 8;     // 0..24
            *(bf16x8*)&sA[r][c8] = *(const bf16x8*)&A [(size_t)(row0 + r) * 2048 + k0 + c8];
            *(bf16x8*)&sB[r][c8] = *(const bf16x8*)&Wb[(size_t)(col0 + r) * 2048 + k0 + c8];
        }
        __syncthreads();

        bf16x8 a_f[4], b_f[4];
        #pragma unroll
        for (int f = 0; f < 4; ++f) {
            a_f[f] = *(const bf16x8*)&sA[wm + f * 16 + frow][fkoff];
            b_f[f] = *(const bf16x8*)&sB[wn + f * 16 + frow][fkoff];
        }
        #pragma unroll
        for (int fm = 0; fm < 4; ++fm)
            #pragma unroll
            for (int fn = 0; fn < 4; ++fn)
                acc[fm][fn] = __builtin_amdgcn_mfma_f32_16x16x32_bf16(a_f[fm], b_f[fn], acc[fm][fn], 0, 0, 0);
        __syncthreads();
    }

    const int crow = (lane >> 4) * 4;
    const int ccol = lane & 15;
    #pragma unroll
    for (int fm = 0; fm < 4; ++fm)
        #pragma unroll
        for (int fn = 0; fn < 4; ++fn)
            #pragma unroll
            for (int j = 0; j < 4; ++j) {
                int rg = row0 + wm + fm * 16 + crow + j;
                int cg = col0 + wn + fn * 16 + ccol;
                O[(size_t)rg * 1024 + cg] = tanhf(acc[fm][fn][j] + bias[cg]);
            }
}

// ---------------------------------------------------------------------------
extern "C" void kernel_launch(void* const* d_in, const int* in_sizes, int n_in,
                              void* d_out, int out_size, void* d_ws, size_t ws_size,
                              hipStream_t stream)
{
    const float* x     = (const float*)d_in[0];
    const float* W_in  = (const float*)d_in[1];
    const float* b_in  = (const float*)d_in[2];
    const float* leak  = (const float*)d_in[3];
    const float* thr   = (const float*)d_in[4];
    const float* W_out = (const float*)d_in[5];
    const float* b_out = (const float*)d_in[6];

    // ws: [0,64MiB) comb bf16 ; [64MiB, 64MiB+4MiB) Wb bf16
    const size_t NEED = (64ull << 20) + (4ull << 20);
    if (ws_size < NEED) return;   // (round 3 proved ws >= 96 MiB)

    float*  out  = (float*)d_out;   // also I scratch
    __bf16* comb = (__bf16*)d_ws;
    __bf16* Wb   = (__bf16*)((char*)d_ws + (64ull << 20));

    dim3 grid(8, 128);

    wcvt_kernel<<<1024, 256, 0, stream>>>(W_out, Wb);   // 2M elems / 8 per thread
    gemm1_f32chain_kernel<<<grid, 256, 0, stream>>>(x, W_in, b_in, out);
    hsru_scan_f32_kernel<<<256, 64, 0, stream>>>(out, leak, thr, comb);
    gemm2_kernel<<<grid, 256, 0, stream>>>(comb, Wb, b_out, out);
}

// Round 10
// 576.097 us; speedup vs baseline: 1.1653x; 1.1653x over previous
//
#include <hip/hip_runtime.h>
#include <hip/hip_bf16.h>
#include <cmath>

// Problem dims (fixed): B=16, T=1024, IN=1024, H=1024
// M = B*T = 16384, K1 = 1024, N1 = 1024, K2 = 2048, N2 = 1024
//
// Numerics contract (validated round 5): GEMM1 must be a sequential
// ascending-k f32 FMA chain per output element + separate f32 bias add
// (mirrors the np golden's BLAS sgemm). Scan mirrors numpy f32 op-for-op.
// GEMM2 (smooth tanh) is bf16 MFMA.
//
// Round 10: RECOMBINATION of measured-best components:
//  - gemm1: exact round-6 kernel (454 us; padded LDF=36, 0 conflicts,
//    2-barrier K-loop, immediate reg-staging, VGPR 104, 4 blocks/CU).
//    r7 (global_load_lds+XOR), r8 (reg prefetch), r9 (LDS ping-pong) all
//    regressed: compiler + 4-block TLP already covers the latency; explicit
//    pipelining pays more in VGPR/LDS/occupancy than it hides.
//  - scan: r9 16-deep prefetch ring, 256 blocks x 64 thr.
//  - gemm2: r8 bf16-preconverted W_out (wcvt) staging.

typedef __attribute__((ext_vector_type(8))) __bf16 bf16x8;
typedef __attribute__((ext_vector_type(4))) __bf16 bf16x4;
typedef __attribute__((ext_vector_type(4))) float  f32x4;

#define LDT 40  // bf16 LDS pad (GEMM2): 80B rows
#define LDF 36  // f32 LDS pad (GEMM1): 144B rows — measured 0 bank conflicts

// ---------------------------------------------------------------------------
// GEMM1 (f32 FMA-chain): I[m,h] = fadd( fmaf-chain_{k=0..1023}, b_in[h] )
// ---------------------------------------------------------------------------
__global__ __launch_bounds__(256)
void gemm1_f32chain_kernel(const float* __restrict__ X,
                           const float* __restrict__ W,
                           const float* __restrict__ bias,
                           float* __restrict__ I)
{
    __shared__ __align__(16) float sA[128][LDF];
    __shared__ __align__(16) float sB[128][LDF];

    const int tid  = threadIdx.x;
    const int bn   = blockIdx.x;      // 0..7
    const int bm   = blockIdx.y;      // 0..127
    const int row0 = bm * 128;
    const int col0 = bn * 128;
    const int tx   = tid & 15;
    const int ty   = tid >> 4;

    float acc[8][8];
    #pragma unroll
    for (int i = 0; i < 8; ++i)
        #pragma unroll
        for (int j = 0; j < 8; ++j)
            acc[i][j] = 0.0f;

    for (int k0 = 0; k0 < 1024; k0 += 32) {
        #pragma unroll
        for (int i = 0; i < 4; ++i) {
            int q  = tid + i * 256;   // 0..1023
            int r  = q >> 3;          // 0..127
            int c4 = (q & 7) * 4;     // 0..28
            *(f32x4*)&sA[r][c4] = *(const f32x4*)&X[(size_t)(row0 + r) * 1024 + k0 + c4];
            *(f32x4*)&sB[r][c4] = *(const f32x4*)&W[(size_t)(col0 + r) * 1024 + k0 + c4];
        }
        __syncthreads();

        // ds_read_b128: 4 consecutive k per row per read. FMA order strictly
        // ascending k (kk group ascending, q ascending within it).
        #pragma unroll
        for (int kk = 0; kk < 32; kk += 4) {
            f32x4 a4[8], b4[8];
            #pragma unroll
            for (int i = 0; i < 8; ++i) a4[i] = *(const f32x4*)&sA[ty + 16 * i][kk];
            #pragma unroll
            for (int j = 0; j < 8; ++j) b4[j] = *(const f32x4*)&sB[tx + 16 * j][kk];
            #pragma unroll
            for (int q = 0; q < 4; ++q)
                #pragma unroll
                for (int i = 0; i < 8; ++i)
                    #pragma unroll
                    for (int j = 0; j < 8; ++j)
                        acc[i][j] = fmaf(a4[i][q], b4[j][q], acc[i][j]);
        }
        __syncthreads();
    }

    #pragma unroll
    for (int i = 0; i < 8; ++i)
        #pragma unroll
        for (int j = 0; j < 8; ++j) {
            int rg = row0 + ty + 16 * i;
            int cg = col0 + tx + 16 * j;
            I[(size_t)rg * 1024 + cg] = __fadd_rn(acc[i][j], bias[cg]);
        }
}

// ---------------------------------------------------------------------------
// Scan, numpy-f32 mirror (validated):
//   alpha = expf(-logaddexpf(lt,0)) via round-to-f32 of f64 libm
//   v = fadd(fmul(alpha, v), I); spike = v > thr; v = fmul(v, 1-spike)
// 16-deep static prefetch ring; 1 wave per block, 256 blocks (all CUs busy).
// ---------------------------------------------------------------------------
__global__ __launch_bounds__(64)
void hsru_scan_f32_kernel(const float* __restrict__ I,
                          const float* __restrict__ leak,
                          const float* __restrict__ thr,
                          __bf16* __restrict__ comb)
{
    int g = blockIdx.x * 64 + threadIdx.x;  // 0..16383
    int b = g >> 10;
    int h = g & 1023;

    float lt = leak[h];
    float e     = (float)exp(-(double)fabsf(lt));
    float l1    = (float)log1p((double)e);
    float sp    = __fadd_rn(fmaxf(lt, 0.0f), l1);
    float alpha = (float)exp(-(double)sp);
    float th    = thr[h];

    const float* Ip = I    + (size_t)b * (1024 * 1024) + h;
    __bf16*      cp = comb + (size_t)b * (1024 * 2048) + h;

    float buf[16], nxt[16];
    #pragma unroll
    for (int j = 0; j < 16; ++j) buf[j] = Ip[(size_t)j * 1024];

    float v = 0.0f;
    for (int t0 = 0; t0 < 1024; t0 += 16) {
        if (t0 + 16 < 1024) {
            #pragma unroll
            for (int j = 0; j < 16; ++j)
                nxt[j] = Ip[(size_t)(t0 + 16 + j) * 1024];
        }
        #pragma unroll
        for (int j = 0; j < 16; ++j) {
            float cur = buf[j];
            v = __fadd_rn(__fmul_rn(alpha, v), cur);
            float spike = (v > th) ? 1.0f : 0.0f;
            v = __fmul_rn(v, __fsub_rn(1.0f, spike));
            cp[(size_t)(t0 + j) * 2048]        = (__bf16)v;
            cp[(size_t)(t0 + j) * 2048 + 1024] = (__bf16)spike;
        }
        if (t0 + 16 < 1024) {
            #pragma unroll
            for (int j = 0; j < 16; ++j) buf[j] = nxt[j];
        }
    }
}

// ---------------------------------------------------------------------------
// W_out f32 -> bf16 pre-convert (once per launch; 2M elements)
// ---------------------------------------------------------------------------
__global__ __launch_bounds__(256)
void wcvt_kernel(const float* __restrict__ W, __bf16* __restrict__ Wb)
{
    int idx = (blockIdx.x * 256 + threadIdx.x) * 8;   // 8 elements/thread
    f32x4 v0 = *(const f32x4*)&W[idx];
    f32x4 v1 = *(const f32x4*)&W[idx + 4];
    bf16x8 o;
    #pragma unroll
    for (int j = 0; j < 4; ++j) { o[j] = (__bf16)v0[j]; o[4 + j] = (__bf16)v1[j]; }
    *(bf16x8*)&Wb[idx] = o;
}

// ---------------------------------------------------------------------------
// GEMM2: out = tanh(combined @ Wb^T + b_out), bf16 MFMA (smooth path).
// A = comb [M,2048] bf16, B = Wb [1024,2048] bf16 (pre-converted)
// ---------------------------------------------------------------------------
__global__ __launch_bounds__(256)
void gemm2_kernel(const __bf16* __restrict__ A,
                  const __bf16* __restrict__ Wb,
                  const float* __restrict__ bias,
                  float* __restrict__ O)
{
    __shared__ __align__(16) __bf16 sA[128][LDT];
    __shared__ __align__(16) __bf16 sB[128][LDT];

    const int tid  = threadIdx.x;
    const int bn   = blockIdx.x;
    const int bm   = blockIdx.y;
    const int row0 = bm * 128;
    const int col0 = bn * 128;

    const int lane = tid & 63;
    const int wid  = tid >> 6;
    const int wm   = (wid >> 1) * 64;
    const int wn   = (wid & 1) * 64;

    f32x4 acc[4][4];
    #pragma unroll
    for (int i = 0; i < 4; ++i)
        #pragma unroll
        for (int j = 0; j < 4; ++j)
            acc[i][j] = f32x4{0.f, 0.f, 0.f, 0.f};

    const int frow  = lane & 15;
    const int fkoff = (lane >> 4) * 8;

    for (int k0 = 0; k0 < 2048; k0 += 32) {
        #pragma unroll
        for (int i = 0; i < 2; ++i) {
            int q  = tid + i * 256;   // 0..511
            int r  = q >> 2;          // 0..127
            int c8 = (q & 3) * 8;     // 0..24
            *(bf16x8*)&sA[r][c8] = *(const bf16x8*)&A [(size_t)(row0 + r) * 2048 + k0 + c8];
            *(bf16x8*)&sB[r][c8] = *(const bf16x8*)&Wb[(size_t)(col0 + r) * 2048 + k0 + c8];
        }
        __syncthreads();

        bf16x8 a_f[4], b_f[4];
        #pragma unroll
        for (int f = 0; f < 4; ++f) {
            a_f[f] = *(const bf16x8*)&sA[wm + f * 16 + frow][fkoff];
            b_f[f] = *(const bf16x8*)&sB[wn + f * 16 + frow][fkoff];
        }
        #pragma unroll
        for (int fm = 0; fm < 4; ++fm)
            #pragma unroll
            for (int fn = 0; fn < 4; ++fn)
                acc[fm][fn] = __builtin_amdgcn_mfma_f32_16x16x32_bf16(a_f[fm], b_f[fn], acc[fm][fn], 0, 0, 0);
        __syncthreads();
    }

    const int crow = (lane >> 4) * 4;
    const int ccol = lane & 15;
    #pragma unroll
    for (int fm = 0; fm < 4; ++fm)
        #pragma unroll
        for (int fn = 0; fn < 4; ++fn)
            #pragma unroll
            for (int j = 0; j < 4; ++j) {
                int rg = row0 + wm + fm * 16 + crow + j;
                int cg = col0 + wn + fn * 16 + ccol;
                O[(size_t)rg * 1024 + cg] = tanhf(acc[fm][fn][j] + bias[cg]);
            }
}

// ---------------------------------------------------------------------------
extern "C" void kernel_launch(void* const* d_in, const int* in_sizes, int n_in,
                              void* d_out, int out_size, void* d_ws, size_t ws_size,
                              hipStream_t stream)
{
    const float* x     = (const float*)d_in[0];
    const float* W_in  = (const float*)d_in[1];
    const float* b_in  = (const float*)d_in[2];
    const float* leak  = (const float*)d_in[3];
    const float* thr   = (const float*)d_in[4];
    const float* W_out = (const float*)d_in[5];
    const float* b_out = (const float*)d_in[6];

    // ws: [0,64MiB) comb bf16 ; [64MiB, 64MiB+4MiB) Wb bf16
    const size_t NEED = (64ull << 20) + (4ull << 20);
    if (ws_size < NEED) return;   // (round 3 proved ws >= 96 MiB)

    float*  out  = (float*)d_out;   // also I scratch
    __bf16* comb = (__bf16*)d_ws;
    __bf16* Wb   = (__bf16*)((char*)d_ws + (64ull << 20));

    dim3 grid(8, 128);

    wcvt_kernel<<<1024, 256, 0, stream>>>(W_out, Wb);   // 2M elems / 8 per thread
    gemm1_f32chain_kernel<<<grid, 256, 0, stream>>>(x, W_in, b_in, out);
    hsru_scan_f32_kernel<<<256, 64, 0, stream>>>(out, leak, thr, comb);
    gemm2_kernel<<<grid, 256, 0, stream>>>(comb, Wb, b_out, out);
}